// Round 5
// baseline (22.711 us; speedup 1.0000x reference)
//
#include <hip/hip_runtime.h>
#include <hip/hip_bf16.h>
#include <math.h>

#define NLINES 128
#define BUFLEN 48000
#define KLEN   96000
#define NBINS  64
#define TAP1   47936              // tap base in p-space (p = m+1, aligned buffer)
#define PSLOW  47616              // exact-tail region start
#define NG8    5952               // 8-sample groups in [0, PSLOW)
#define CH     4                  // moment chunks per line
#define GCH    (NG8/CH)           // 1488 groups per chunk
#define TB     2                  // tail blocks per line
#define ROLES  (CH+TB)

#define INV2K  5.2083333333333333e-06f  // 1/(2K): revolutions per sample
#define DLT_F  3.2724923474893679e-05f  // pi/K rad
#define T05    1.6362461737446e-05f     // tan(0.5*pi/K)
#define T15    4.9087385252705e-05f     // tan(1.5*pi/K)
#define T25    8.1812308687e-05f        // tan(2.5*pi/K)
#define T35    1.1453723216e-04f        // tan(3.5*pi/K)

__device__ __forceinline__ float wave_reduce(float v){
  #pragma unroll
  for (int off = 32; off; off >>= 1) v += __shfl_down(v, off, 64);
  return v;
}

__device__ __forceinline__ float sin_pi_d(float d){
  // sin(pi*d): d = r+f, |f|<=0.5 -> (-1)^r sin(pi f)
  const float r = rintf(d);
  float sp = __builtin_amdgcn_sinf(0.5f * (d - r));
  if (((int)r) & 1) sp = -sp;
  return sp;
}

// out[line] = sum_j filt_j * tap_j;  tap_j = sum_p v_p h(x), x = (TAP1+j-p)-d,
// h = (-1)^(s+1) sin(pi d)/K cot(pi x/K).
// Moment blocks (p < PSLOW, |x| >= ~292): quartic Taylor moments of cot around
// the 64-tap center; one sin/cos/rcp per 8 samples via the exact identity
// cot(t+b) = (c - s tan b)/(s + c tan b) + 8-way batch inversion. Output is
// linear in moments -> each block folds filter dot locally, atomicAdds scalar.
// Tail blocks: exact per-(p,j) eval on the 385-sample window (hits via x==0).
__global__ __launch_bounds__(256) void frac_delay_fused(
    const float* __restrict__ buffer, const float* __restrict__ inputs,
    const float* __restrict__ delays, const float* __restrict__ filt,
    float* __restrict__ out)
{
  const int line = blockIdx.x / ROLES;
  const int role = blockIdx.x % ROLES;
  const int tid  = threadIdx.x;

  __shared__ float red[4][5];
  __shared__ float mom[5];
  __shared__ float tred[4];

  const float d = delays[line];
  const float scale0 = sin_pi_d(d) * (1.0f / (float)KLEN);
  const float* __restrict__ bufline = buffer + (size_t)line * BUFLEN;

  if (role < CH){
    // ---------------- moment block ----------------
    const float cb = 47964.0f - d;          // x at group center (i=3.5) = cb - P
    float A0=0.f, A1=0.f, A2=0.f, A3=0.f, A4=0.f;
    const int gend = role * GCH + GCH;
    for (int g = role * GCH + tid; g < gend; g += 256){
      const int P = g << 3;
      float4 va = *reinterpret_cast<const float4*>(bufline + P);
      float4 vb = *reinterpret_cast<const float4*>(bufline + P + 4);
      if (P == 0) va.x = 0.f;               // p=0 excluded by the roll
      const float tr = (cb - (float)P) * INV2K;
      const float s  = __builtin_amdgcn_sinf(tr);
      const float c  = __builtin_amdgcn_cosf(tr);

      const float TBL[8] = {T35, T25, T15, T05, -T05, -T15, -T25, -T35};
      const float vv[8]  = {va.x, va.y, va.z, va.w, vb.x, vb.y, vb.z, vb.w};
      float N[8], D[8], Pp[8], w[8];
      #pragma unroll
      for (int i = 0; i < 8; ++i){
        N[i] = fmaf(s, -TBL[i], c);
        D[i] = fmaf(c,  TBL[i], s);
      }
      Pp[0] = D[0];
      #pragma unroll
      for (int i = 1; i < 8; ++i) Pp[i] = Pp[i-1] * D[i];
      float inv = __builtin_amdgcn_rcpf(Pp[7]);
      #pragma unroll
      for (int i = 7; i >= 1; --i){ w[i] = N[i] * (inv * Pp[i-1]); inv *= D[i]; }
      w[0] = N[0] * inv;

      #pragma unroll
      for (int i = 0; i < 8; ++i){
        const float vp = (i & 1) ? -vv[i] : vv[i];   // (-1)^p, P even
        const float W  = w[i];
        const float w2 = W * W;
        const float u  = w2 + 1.0f;
        A0 = fmaf(vp, W, A0);
        const float vu = vp * u;
        A1 += vu;
        const float t2 = vu * W;
        A2 += t2;
        const float e3 = fmaf(3.0f, w2, 1.0f);
        A3 = fmaf(vu, e3, A3);
        A4 = fmaf(t2, e3 + 1.0f, A4);
      }
    }

    const int lane = tid & 63, wv = tid >> 6;
    float vals[5] = {A0, A1, A2, A3, A4};
    #pragma unroll
    for (int k = 0; k < 5; ++k){
      float x = wave_reduce(vals[k]);
      if (lane == 0) red[wv][k] = x;
    }
    __syncthreads();
    if (tid < 5) mom[tid] = red[0][tid] + red[1][tid] + red[2][tid] + red[3][tid];
    __syncthreads();
    if (tid < 64){
      // cot series: w - uY + wuY^2 - u(1+3w^2)Y^3/3 + wu(2+3w^2)Y^4/3
      const float Y = ((float)tid - 31.5f) * DLT_F;
      float h =          mom[4] * (1.0f/3.0f);
      h = fmaf(h, Y,    -mom[3] * (1.0f/3.0f));
      h = fmaf(h, Y,     mom[2]);
      h = fmaf(h, Y,    -mom[1]);
      h = fmaf(h, Y,     mom[0]);
      const float sg = (tid & 1) ? 1.0f : -1.0f;     // (-1)^(j+1)
      float val = sg * scale0 * h * filt[line * NBINS + tid];
      val = wave_reduce(val);
      if (tid == 0) unsafeAtomicAdd(&out[line], val);
    }
  } else {
    // ---------------- tail block (exact) ----------------
    const int j  = tid & 63;
    const int pg = (tid >> 6) + (role - CH) * 4;     // 0..7
    const int jj = TAP1 + j;
    const float inputv = inputs[line];
    float tj = 0.f;
    for (int p = PSLOW + pg; p <= BUFLEN; p += 8){
      const float v = (p < BUFLEN) ? bufline[p] : inputv;  // p=BUFLEN: new sample
      const float x = (float)(jj - p) - d;           // exact small ints - d
      float term;
      if (x == 0.0f) term = v;                       // exact integer-delay hit
      else {
        const float tr = x * INV2K;
        const float ct = __builtin_amdgcn_cosf(tr) *
                         __builtin_amdgcn_rcpf(__builtin_amdgcn_sinf(tr));
        const float sg = ((j + p) & 1) ? 1.0f : -1.0f;  // (-1)^(s+1)
        term = sg * scale0 * v * ct;
      }
      tj += term;
    }
    float val = tj * filt[line * NBINS + j];
    val = wave_reduce(val);                          // sums over j within wave
    if ((tid & 63) == 0) tred[tid >> 6] = val;
    __syncthreads();
    if (tid == 0)
      unsafeAtomicAdd(&out[line], tred[0] + tred[1] + tred[2] + tred[3]);
  }
}

extern "C" void kernel_launch(void* const* d_in, const int* in_sizes, int n_in,
                              void* d_out, int out_size, void* d_ws, size_t ws_size,
                              hipStream_t stream)
{
  const float* buffer = (const float*)d_in[0];
  const float* inputs = (const float*)d_in[1];
  const float* delays = (const float*)d_in[2];
  const float* filt   = (const float*)d_in[3];
  float* out = (float*)d_out;

  hipMemsetAsync(out, 0, (size_t)out_size * sizeof(float), stream);
  frac_delay_fused<<<NLINES * ROLES, 256, 0, stream>>>(buffer, inputs, delays, filt, out);
}

// Round 6
// 17.616 us; speedup vs baseline: 1.2892x; 1.2892x over previous
//
#include <hip/hip_runtime.h>
#include <hip/hip_bf16.h>
#include <math.h>

#define NLINES 128
#define BUFLEN 48000
#define KLEN   96000
#define NBINS  64
#define TAP1   47936              // tap base in p-space (p = m+1, aligned buffer)
#define PSLOW  47616              // exact-tail region start
#define NG8    5952               // 8-sample groups in [0, PSLOW)
#define NTHR   1024
#define NW     16                 // waves per block

#define INV2K  5.2083333333333333e-06f  // 1/(2K): revolutions per sample
#define DLT_F  3.2724923474893679e-05f  // pi/K rad
#define T05    1.6362461737446e-05f     // tan(0.5*pi/K)
#define T15    4.9087385252705e-05f     // tan(1.5*pi/K)
#define T25    8.1812308687e-05f        // tan(2.5*pi/K)
#define T35    1.1453723216e-04f        // tan(3.5*pi/K)

__device__ __forceinline__ float wave_reduce(float v){
  #pragma unroll
  for (int off = 32; off; off >>= 1) v += __shfl_down(v, off, 64);
  return v;
}

__device__ __forceinline__ float sin_pi_d(float d){
  // sin(pi*d): d = r+f, |f|<=0.5 -> (-1)^r sin(pi f)
  const float r = rintf(d);
  float sp = __builtin_amdgcn_sinf(0.5f * (d - r));
  if (((int)r) & 1) sp = -sp;
  return sp;
}

// One block per line. out[line] = sum_j filt_j * tap_j;
// tap_j = sum_p v_p h(x), x = (TAP1+j-p)-d, h = (-1)^(s+1) sin(pi d)/K cot(pi x/K).
// Moments phase (p < PSLOW, |x_c| >= ~292): quartic Taylor moments of cot
// around the 64-tap center; one sin/cos/rcp per 8 samples via
// cot(t+b) = (c - s tan b)/(s + c tan b) + 8-way batch inversion.
// Tail phase: exact per-(p,j) eval on the 385-sample pole window (hits via x==0).
__global__ __launch_bounds__(NTHR) void frac_delay_line(
    const float* __restrict__ buffer, const float* __restrict__ inputs,
    const float* __restrict__ delays, const float* __restrict__ filt,
    float* __restrict__ out)
{
  const int line = blockIdx.x;
  const int tid  = threadIdx.x;
  const int lane = tid & 63, wv = tid >> 6;

  __shared__ float redM[NW][5];
  __shared__ float redT[NW][NBINS];

  const float d = delays[line];
  const float scale0 = sin_pi_d(d) * (1.0f / (float)KLEN);
  const float* __restrict__ bufline = buffer + (size_t)line * BUFLEN;

  // ---------------- moments phase ----------------
  const float cb = 47964.0f - d;            // x at group center (i=3.5) = cb - P
  float A0=0.f, A1=0.f, A2=0.f, A3=0.f, A4=0.f;
  for (int g = tid; g < NG8; g += NTHR){
    const int P = g << 3;
    float4 va = *reinterpret_cast<const float4*>(bufline + P);
    float4 vb = *reinterpret_cast<const float4*>(bufline + P + 4);
    if (P == 0) va.x = 0.f;                 // p=0 excluded by the roll
    const float tr = (cb - (float)P) * INV2K;
    const float s  = __builtin_amdgcn_sinf(tr);
    const float c  = __builtin_amdgcn_cosf(tr);

    const float TBL[8] = {T35, T25, T15, T05, -T05, -T15, -T25, -T35};
    const float vv[8]  = {va.x, va.y, va.z, va.w, vb.x, vb.y, vb.z, vb.w};
    float N[8], D[8], Pp[8], w[8];
    #pragma unroll
    for (int i = 0; i < 8; ++i){
      N[i] = fmaf(s, -TBL[i], c);
      D[i] = fmaf(c,  TBL[i], s);
    }
    Pp[0] = D[0];
    #pragma unroll
    for (int i = 1; i < 8; ++i) Pp[i] = Pp[i-1] * D[i];
    float inv = __builtin_amdgcn_rcpf(Pp[7]);
    #pragma unroll
    for (int i = 7; i >= 1; --i){ w[i] = N[i] * (inv * Pp[i-1]); inv *= D[i]; }
    w[0] = N[0] * inv;

    #pragma unroll
    for (int i = 0; i < 8; ++i){
      const float vp = (i & 1) ? -vv[i] : vv[i];   // (-1)^p, P even
      const float W  = w[i];
      const float w2 = W * W;
      const float u  = w2 + 1.0f;
      A0 = fmaf(vp, W, A0);
      const float vu = vp * u;
      A1 += vu;
      const float t2 = vu * W;
      A2 += t2;
      const float e3 = fmaf(3.0f, w2, 1.0f);
      A3 = fmaf(vu, e3, A3);
      A4 = fmaf(t2, e3 + 1.0f, A4);
    }
  }

  // ---------------- tail phase (exact) ----------------
  // wave wv handles p = PSLOW+wv, +16, ...; lane = tap j (broadcast loads)
  const int j  = lane;
  const int jj = TAP1 + j;
  const float inputv = inputs[line];
  float tj = 0.f;
  for (int p = PSLOW + wv; p <= BUFLEN; p += NW){
    const float v = (p < BUFLEN) ? bufline[p] : inputv;   // p=BUFLEN: new sample
    const float x = (float)(jj - p) - d;
    float term;
    if (x == 0.0f) term = v;                              // integer-delay hit
    else {
      const float tr = x * INV2K;
      const float ct = __builtin_amdgcn_cosf(tr) *
                       __builtin_amdgcn_rcpf(__builtin_amdgcn_sinf(tr));
      const float sg = ((j + p) & 1) ? 1.0f : -1.0f;      // (-1)^(s+1)
      term = sg * scale0 * v * ct;
    }
    tj += term;
  }

  // ---------------- reduce & output ----------------
  float vals[5] = {A0, A1, A2, A3, A4};
  #pragma unroll
  for (int k = 0; k < 5; ++k){
    float x = wave_reduce(vals[k]);
    if (lane == 0) redM[wv][k] = x;
  }
  redT[wv][j] = tj;
  __syncthreads();

  if (wv == 0){
    float mom[5];
    #pragma unroll
    for (int k = 0; k < 5; ++k){
      float s = 0.f;
      #pragma unroll
      for (int w = 0; w < NW; ++w) s += redM[w][k];
      mom[k] = s;
    }
    float tail = 0.f;
    #pragma unroll
    for (int w = 0; w < NW; ++w) tail += redT[w][lane];

    // cot series: w - uY + wuY^2 - u(1+3w^2)Y^3/3 + wu(2+3w^2)Y^4/3
    const float Y = ((float)lane - 31.5f) * DLT_F;
    float h =          mom[4] * (1.0f/3.0f);
    h = fmaf(h, Y,    -mom[3] * (1.0f/3.0f));
    h = fmaf(h, Y,     mom[2]);
    h = fmaf(h, Y,    -mom[1]);
    h = fmaf(h, Y,     mom[0]);
    const float sg = (lane & 1) ? 1.0f : -1.0f;           // (-1)^(j+1)
    const float tap = fmaf(sg * scale0, h, tail);
    float val = tap * filt[line * NBINS + lane];
    val = wave_reduce(val);
    if (lane == 0) out[line] = val;
  }
}

extern "C" void kernel_launch(void* const* d_in, const int* in_sizes, int n_in,
                              void* d_out, int out_size, void* d_ws, size_t ws_size,
                              hipStream_t stream)
{
  const float* buffer = (const float*)d_in[0];
  const float* inputs = (const float*)d_in[1];
  const float* delays = (const float*)d_in[2];
  const float* filt   = (const float*)d_in[3];
  float* out = (float*)d_out;

  frac_delay_line<<<NLINES, NTHR, 0, stream>>>(buffer, inputs, delays, filt, out);
}

// Round 7
// 15.178 us; speedup vs baseline: 1.4963x; 1.1606x over previous
//
#include <hip/hip_runtime.h>
#include <hip/hip_bf16.h>
#include <math.h>

#define NLINES 128
#define BUFLEN 48000
#define KLEN   96000
#define NBINS  64
#define TAP1   47936              // tap base in p-space (p = m+1, aligned buffer)
#define PSLOW  47840              // exact-tail region start (|x| >= 65 guaranteed)
#define NG8    5980               // 8-sample groups in [0, PSLOW)
#define NFULL  5                  // full strided passes (5*1024 groups)
#define NREST  860                // remaining groups (tid < NREST)
#define NTHR   1024
#define NW     16                 // waves per block
#define NTK    10                 // tail iterations per wave (160 = 16*10)

#define INV2K  5.2083333333333333e-06f  // 1/(2K): revolutions per sample
#define DLT_F  3.2724923474893679e-05f  // pi/K rad
#define T05    1.6362461737446e-05f     // tan(0.5*pi/K)
#define T15    4.9087385252705e-05f     // tan(1.5*pi/K)
#define T25    8.1812308687e-05f        // tan(2.5*pi/K)
#define T35    1.1453723216e-04f        // tan(3.5*pi/K)

__device__ __forceinline__ float wave_reduce(float v){
  #pragma unroll
  for (int off = 32; off; off >>= 1) v += __shfl_down(v, off, 64);
  return v;
}

__device__ __forceinline__ float sin_pi_d(float d){
  // sin(pi*d): d = r+f, |f|<=0.5 -> (-1)^r sin(pi f)
  const float r = rintf(d);
  float sp = __builtin_amdgcn_sinf(0.5f * (d - r));
  if (((int)r) & 1) sp = -sp;
  return sp;
}

// One block per line. out[line] = sum_j filt_j * tap_j;
// tap_j = sum_p v_p h(x), x = (TAP1+j-p)-d, h = (-1)^(s+1) sin(pi d)/K cot(pi x/K).
// Moments phase (p < PSLOW): quartic Taylor moments of cot around the 64-tap
// center; one sin/cos/rcp per 8 samples via cot(t+b) = (c - s tan b)/(s + c tan b)
// + 8-way batch inversion. Tail phase: exact per-(p,j) on the 161-sample window.
__global__ __launch_bounds__(NTHR) void frac_delay_line(
    const float* __restrict__ buffer, const float* __restrict__ inputs,
    const float* __restrict__ delays, const float* __restrict__ filt,
    float* __restrict__ out)
{
  const int line = blockIdx.x;
  const int tid  = threadIdx.x;
  const int lane = tid & 63, wv = tid >> 6;

  __shared__ float redM[NW][5];
  __shared__ float redT[NW][NBINS];

  const float d = delays[line];
  const float scale0 = sin_pi_d(d) * (1.0f / (float)KLEN);
  const float* __restrict__ bufline = buffer + (size_t)line * BUFLEN;

  // ---------------- moments phase ----------------
  const float cb = 47964.0f - d;            // x at group center (i=3.5) = cb - P
  float A0=0.f, A1=0.f, A2=0.f, A3=0.f, A4=0.f;

  auto moment8 = [&](int P, float4 va, float4 vb){
    const float tr = (cb - (float)P) * INV2K;
    const float s  = __builtin_amdgcn_sinf(tr);
    const float c  = __builtin_amdgcn_cosf(tr);
    const float TBL[8] = {T35, T25, T15, T05, -T05, -T15, -T25, -T35};
    const float vv[8]  = {va.x, va.y, va.z, va.w, vb.x, vb.y, vb.z, vb.w};
    float N[8], D[8], Pp[8], w[8];
    #pragma unroll
    for (int i = 0; i < 8; ++i){
      N[i] = fmaf(s, -TBL[i], c);
      D[i] = fmaf(c,  TBL[i], s);
    }
    Pp[0] = D[0];
    #pragma unroll
    for (int i = 1; i < 8; ++i) Pp[i] = Pp[i-1] * D[i];
    float inv = __builtin_amdgcn_rcpf(Pp[7]);
    #pragma unroll
    for (int i = 7; i >= 1; --i){ w[i] = N[i] * (inv * Pp[i-1]); inv *= D[i]; }
    w[0] = N[0] * inv;
    #pragma unroll
    for (int i = 0; i < 8; ++i){
      const float vp = (i & 1) ? -vv[i] : vv[i];   // (-1)^p, P even
      const float W  = w[i];
      const float w2 = W * W;
      const float u  = w2 + 1.0f;
      A0 = fmaf(vp, W, A0);
      const float vu = vp * u;
      A1 += vu;
      const float t2 = vu * W;
      A2 += t2;
      const float e3 = fmaf(3.0f, w2, 1.0f);
      A3 = fmaf(vu, e3, A3);
      A4 = fmaf(t2, e3 + 1.0f, A4);
    }
  };

  // rolling 1-ahead prefetch, static trip count (5 full + 1 predicated)
  {
    int P = tid << 3;
    float4 va = *reinterpret_cast<const float4*>(bufline + P);
    float4 vb = *reinterpret_cast<const float4*>(bufline + P + 4);
    if (tid == 0) va.x = 0.f;               // p=0 excluded by the roll
    #pragma unroll
    for (int k = 0; k < NFULL; ++k){
      int Pn = 0; float4 na, nb;
      const bool more = (k < NFULL - 1) || (tid < NREST);
      if (more){
        Pn = (k < NFULL - 1) ? ((tid + (k + 1) * NTHR) << 3)
                             : ((NFULL * NTHR + tid) << 3);
        na = *reinterpret_cast<const float4*>(bufline + Pn);
        nb = *reinterpret_cast<const float4*>(bufline + Pn + 4);
      }
      moment8(P, va, vb);
      P = Pn; va = na; vb = nb;
    }
    if (tid < NREST) moment8(P, va, vb);
  }

  // ---------------- tail phase (exact) ----------------
  // wave wv handles p = PSLOW+wv, +16, ...; lane = tap j (broadcast loads)
  const int j  = lane;
  const int jj = TAP1 + j;
  float tj = 0.f;
  #pragma unroll
  for (int k = 0; k < NTK; ++k){
    const int p = PSLOW + wv + (k << 4);
    const float v = bufline[p];
    const float x = (float)(jj - p) - d;
    float term;
    if (x == 0.0f) term = v;                              // integer-delay hit
    else {
      const float tr = x * INV2K;
      const float ct = __builtin_amdgcn_cosf(tr) *
                       __builtin_amdgcn_rcpf(__builtin_amdgcn_sinf(tr));
      const float sg = ((j + p) & 1) ? 1.0f : -1.0f;      // (-1)^(s+1)
      term = sg * scale0 * v * ct;
    }
    tj += term;
  }
  if (wv == 0){                              // p = BUFLEN: the new input sample
    const float v = inputs[line];
    const int   p = BUFLEN;
    const float x = (float)(jj - p) - d;     // in [-96.5,-1], never 0
    const float tr = x * INV2K;
    const float ct = __builtin_amdgcn_cosf(tr) *
                     __builtin_amdgcn_rcpf(__builtin_amdgcn_sinf(tr));
    const float sg = ((j + p) & 1) ? 1.0f : -1.0f;
    tj += sg * scale0 * v * ct;
  }

  // ---------------- reduce & output ----------------
  float vals[5] = {A0, A1, A2, A3, A4};
  #pragma unroll
  for (int k = 0; k < 5; ++k){
    float x = wave_reduce(vals[k]);
    if (lane == 0) redM[wv][k] = x;
  }
  redT[wv][j] = tj;
  __syncthreads();

  if (wv == 0){
    float mom[5];
    #pragma unroll
    for (int k = 0; k < 5; ++k){
      float s = 0.f;
      #pragma unroll
      for (int w = 0; w < NW; ++w) s += redM[w][k];
      mom[k] = s;
    }
    float tail = 0.f;
    #pragma unroll
    for (int w = 0; w < NW; ++w) tail += redT[w][lane];

    // cot series: w - uY + wuY^2 - u(1+3w^2)Y^3/3 + wu(2+3w^2)Y^4/3
    const float Y = ((float)lane - 31.5f) * DLT_F;
    float h =          mom[4] * (1.0f/3.0f);
    h = fmaf(h, Y,    -mom[3] * (1.0f/3.0f));
    h = fmaf(h, Y,     mom[2]);
    h = fmaf(h, Y,    -mom[1]);
    h = fmaf(h, Y,     mom[0]);
    const float sg = (lane & 1) ? 1.0f : -1.0f;           // (-1)^(j+1)
    const float tap = fmaf(sg * scale0, h, tail);
    float val = tap * filt[line * NBINS + lane];
    val = wave_reduce(val);
    if (lane == 0) out[line] = val;
  }
}

extern "C" void kernel_launch(void* const* d_in, const int* in_sizes, int n_in,
                              void* d_out, int out_size, void* d_ws, size_t ws_size,
                              hipStream_t stream)
{
  const float* buffer = (const float*)d_in[0];
  const float* inputs = (const float*)d_in[1];
  const float* delays = (const float*)d_in[2];
  const float* filt   = (const float*)d_in[3];
  float* out = (float*)d_out;

  frac_delay_line<<<NLINES, NTHR, 0, stream>>>(buffer, inputs, delays, filt, out);
}

// Round 8
// 14.213 us; speedup vs baseline: 1.5979x; 1.0678x over previous
//
#include <hip/hip_runtime.h>
#include <hip/hip_bf16.h>
#include <math.h>

#define NLINES 128
#define BUFLEN 48000
#define KLEN   96000
#define NBINS  64
#define TAP1   47936              // tap base in p-space (p = m+1, aligned buffer)
#define PSLOW  47840              // exact-tail region start (|x| >= 65 guaranteed)
#define NG8    5980               // 8-sample groups in [0, PSLOW)
#define G1     3072               // role-0 groups [0,G1): 3 full passes
#define NREST  860                // role-1 rest (after 2 full passes)
#define NTHR   1024
#define NW     16                 // waves per block
#define NTK    10                 // tail iterations per wave (160 = 16*10)

#define INV2K  5.2083333333333333e-06f  // 1/(2K): revolutions per sample
#define DLT_F  3.2724923474893679e-05f  // pi/K rad
#define T05    1.6362461737446e-05f     // tan(0.5*pi/K)
#define T15    4.9087385252705e-05f     // tan(1.5*pi/K)
#define T25    8.1812308687e-05f        // tan(2.5*pi/K)
#define T35    1.1453723216e-04f        // tan(3.5*pi/K)

__device__ __forceinline__ float wave_reduce(float v){
  #pragma unroll
  for (int off = 32; off; off >>= 1) v += __shfl_down(v, off, 64);
  return v;
}

__device__ __forceinline__ float sin_pi_d(float d){
  // sin(pi*d): d = r+f, |f|<=0.5 -> (-1)^r sin(pi f)
  const float r = rintf(d);
  float sp = __builtin_amdgcn_sinf(0.5f * (d - r));
  if (((int)r) & 1) sp = -sp;
  return sp;
}

// Two blocks per line (p-range split); each writes a partial scalar to ws.
// out[line] = sum_j filt_j * tap_j; tap_j = sum_p v_p h(x), x=(TAP1+j-p)-d,
// h = (-1)^(s+1) sin(pi d)/K cot(pi x/K). Output is linear in the quartic
// Taylor moments and additive in the exact tail, so partials just add.
__global__ __launch_bounds__(NTHR) void frac_delay_part(
    const float* __restrict__ buffer, const float* __restrict__ inputs,
    const float* __restrict__ delays, const float* __restrict__ filt,
    float* __restrict__ ws)
{
  const int line = blockIdx.x >> 1;
  const int role = blockIdx.x & 1;
  const int tid  = threadIdx.x;
  const int lane = tid & 63, wv = tid >> 6;

  __shared__ float redM[NW][5];
  __shared__ float redT[NW][NBINS];

  const float d = delays[line];
  const float scale0 = sin_pi_d(d) * (1.0f / (float)KLEN);
  const float* __restrict__ bufline = buffer + (size_t)line * BUFLEN;

  // ---------------- moments phase ----------------
  const float cb = 47964.0f - d;            // x at group center (i=3.5) = cb - P
  float A0=0.f, A1=0.f, A2=0.f, A3=0.f, A4=0.f;

  auto moment8 = [&](int P, float4 va, float4 vb){
    const float tr = (cb - (float)P) * INV2K;
    const float s  = __builtin_amdgcn_sinf(tr);
    const float c  = __builtin_amdgcn_cosf(tr);
    const float TBL[8] = {T35, T25, T15, T05, -T05, -T15, -T25, -T35};
    const float vv[8]  = {va.x, va.y, va.z, va.w, vb.x, vb.y, vb.z, vb.w};
    float N[8], D[8], Pp[8], w[8];
    #pragma unroll
    for (int i = 0; i < 8; ++i){
      N[i] = fmaf(s, -TBL[i], c);
      D[i] = fmaf(c,  TBL[i], s);
    }
    Pp[0] = D[0];
    #pragma unroll
    for (int i = 1; i < 8; ++i) Pp[i] = Pp[i-1] * D[i];
    float inv = __builtin_amdgcn_rcpf(Pp[7]);
    #pragma unroll
    for (int i = 7; i >= 1; --i){ w[i] = N[i] * (inv * Pp[i-1]); inv *= D[i]; }
    w[0] = N[0] * inv;
    #pragma unroll
    for (int i = 0; i < 8; ++i){
      const float vp = (i & 1) ? -vv[i] : vv[i];   // (-1)^p, P even
      const float W  = w[i];
      const float w2 = W * W;
      const float u  = w2 + 1.0f;
      A0 = fmaf(vp, W, A0);
      const float vu = vp * u;
      A1 += vu;
      const float t2 = vu * W;
      A2 += t2;
      const float e3 = fmaf(3.0f, w2, 1.0f);
      A3 = fmaf(vu, e3, A3);
      A4 = fmaf(t2, e3 + 1.0f, A4);
    }
  };

  if (role == 0){
    // groups [0, G1): 3 static full passes, rolling 1-ahead prefetch
    int P = tid << 3;
    float4 va = *reinterpret_cast<const float4*>(bufline + P);
    float4 vb = *reinterpret_cast<const float4*>(bufline + P + 4);
    if (tid == 0) va.x = 0.f;               // p=0 excluded by the roll
    #pragma unroll
    for (int k = 0; k < 3; ++k){
      int Pn = 0; float4 na, nb;
      if (k < 2){
        Pn = (tid + (k + 1) * NTHR) << 3;
        na = *reinterpret_cast<const float4*>(bufline + Pn);
        nb = *reinterpret_cast<const float4*>(bufline + Pn + 4);
      }
      moment8(P, va, vb);
      P = Pn; va = na; vb = nb;
    }
  } else {
    // groups [G1, NG8): 2 full passes + NREST rest, rolling prefetch
    int P = (G1 + tid) << 3;
    float4 va = *reinterpret_cast<const float4*>(bufline + P);
    float4 vb = *reinterpret_cast<const float4*>(bufline + P + 4);
    #pragma unroll
    for (int k = 0; k < 2; ++k){
      int Pn = 0; float4 na, nb;
      const bool more = (k < 1) || (tid < NREST);
      if (more){
        Pn = (G1 + (k + 1) * NTHR + tid) << 3;
        na = *reinterpret_cast<const float4*>(bufline + Pn);
        nb = *reinterpret_cast<const float4*>(bufline + Pn + 4);
      }
      moment8(P, va, vb);
      P = Pn; va = na; vb = nb;
    }
    if (tid < NREST) moment8(P, va, vb);
  }

  // ---------------- tail phase (exact, role 1 only) ----------------
  float tj = 0.f;
  if (role == 1){
    const int j  = lane;
    const int jj = TAP1 + j;
    #pragma unroll
    for (int k = 0; k < NTK; ++k){
      const int p = PSLOW + wv + (k << 4);
      const float v = bufline[p];
      const float x = (float)(jj - p) - d;
      float term;
      if (x == 0.0f) term = v;                            // integer-delay hit
      else {
        const float tr = x * INV2K;
        const float ct = __builtin_amdgcn_cosf(tr) *
                         __builtin_amdgcn_rcpf(__builtin_amdgcn_sinf(tr));
        const float sg = ((j + p) & 1) ? 1.0f : -1.0f;    // (-1)^(s+1)
        term = sg * scale0 * v * ct;
      }
      tj += term;
    }
    if (wv == 0){                            // p = BUFLEN: the new input sample
      const float v = inputs[line];
      const int   p = BUFLEN;
      const float x = (float)(jj - p) - d;   // in [-96.5,-1], never 0
      const float tr = x * INV2K;
      const float ct = __builtin_amdgcn_cosf(tr) *
                       __builtin_amdgcn_rcpf(__builtin_amdgcn_sinf(tr));
      const float sg = ((j + p) & 1) ? 1.0f : -1.0f;
      tj += sg * scale0 * v * ct;
    }
  }

  // ---------------- reduce & partial output ----------------
  float vals[5] = {A0, A1, A2, A3, A4};
  #pragma unroll
  for (int k = 0; k < 5; ++k){
    float x = wave_reduce(vals[k]);
    if (lane == 0) redM[wv][k] = x;
  }
  redT[wv][lane] = tj;
  __syncthreads();

  if (wv == 0){
    float mom[5];
    #pragma unroll
    for (int k = 0; k < 5; ++k){
      float s = 0.f;
      #pragma unroll
      for (int w = 0; w < NW; ++w) s += redM[w][k];
      mom[k] = s;
    }
    float tail = 0.f;
    if (role == 1){
      #pragma unroll
      for (int w = 0; w < NW; ++w) tail += redT[w][lane];
    }
    // cot series: w - uY + wuY^2 - u(1+3w^2)Y^3/3 + wu(2+3w^2)Y^4/3
    const float Y = ((float)lane - 31.5f) * DLT_F;
    float h =          mom[4] * (1.0f/3.0f);
    h = fmaf(h, Y,    -mom[3] * (1.0f/3.0f));
    h = fmaf(h, Y,     mom[2]);
    h = fmaf(h, Y,    -mom[1]);
    h = fmaf(h, Y,     mom[0]);
    const float sg = (lane & 1) ? 1.0f : -1.0f;           // (-1)^(j+1)
    const float tap = fmaf(sg * scale0, h, tail);
    float val = tap * filt[line * NBINS + lane];
    val = wave_reduce(val);
    if (lane == 0) ws[blockIdx.x] = val;
  }
}

// out[line] = ws[2*line] + ws[2*line+1]
__global__ __launch_bounds__(NLINES) void frac_delay_combine(
    const float* __restrict__ ws, float* __restrict__ out)
{
  const int t = threadIdx.x;
  out[t] = ws[2 * t] + ws[2 * t + 1];
}

extern "C" void kernel_launch(void* const* d_in, const int* in_sizes, int n_in,
                              void* d_out, int out_size, void* d_ws, size_t ws_size,
                              hipStream_t stream)
{
  const float* buffer = (const float*)d_in[0];
  const float* inputs = (const float*)d_in[1];
  const float* delays = (const float*)d_in[2];
  const float* filt   = (const float*)d_in[3];
  float* out = (float*)d_out;
  float* ws  = (float*)d_ws;

  frac_delay_part<<<2 * NLINES, NTHR, 0, stream>>>(buffer, inputs, delays, filt, ws);
  frac_delay_combine<<<1, NLINES, 0, stream>>>(ws, out);
}